// Round 2
// baseline (339.665 us; speedup 1.0000x reference)
//
#include <hip/hip_runtime.h>
#include <math.h>

#define NB_PER_BLOCK 8    // batches per 128-thread block
#define ROWSTRIDE 20      // A-row stride in LDS floats (16 data + 4 pad: 16B-aligned float4)
#define MATSTRIDE 644     // per-batch stride (32*20 + 4): skews batches across banks

// phase 1: 16 lanes/batch scan 128 occupancy ints -> sorted occupied-k lists
//          (slots 0..15: up k in [0,64); 16..31: dn k in [64,128)).
// phase 2: cooperative gather, MLP-deepened. 4 lanes own one (batch, A-row):
//          each lane reads ONE float4 (quarter row) per occupied k. k is made
//          wave-uniform via readfirstlane -> SGPR base (W + k*8KB), so each
//          load is global_load_dwordx4 v, v_off, s[base] with a loop-invariant
//          32-bit lane offset: no per-load VALU/ds_read in the chain. Full
//          unroll 32 with 4 independent accumulators -> ~16+ loads in flight
//          per wave (was ~8; latency-bound per Little's law: 120 lines in
//          flight @210cy = 0.57 lines/cy, matches measured 0.38-0.45).
// phase 3: 8-lane LU with implicit partial pivoting (lexicographic tie-break).
// output:  planar complex: out[b] = re, out[B+b] = im.

__global__ __launch_bounds__(128, 4) void backflow_kernel(
    const int* __restrict__ nocc,   // (B,128) int32 0/1
    const float* __restrict__ W,    // (128,2048) f32 row-major
    float* __restrict__ out,        // planar: [B re][B im]
    int B)
{
    __shared__ int lists[NB_PER_BLOCK][33];
    __shared__ float amat[NB_PER_BLOCK * MATSTRIDE];   // 20,608 B

    const int tid = threadIdx.x;

    // ---------------- phase 1: occupancy -> k lists ----------------
    {
        const int bib1 = tid >> 4;                 // 0..7
        const int l16  = tid & 15;
        int batch1 = blockIdx.x * NB_PER_BLOCK + bib1;
        if (batch1 >= B) batch1 = B - 1;
        const int4* np = reinterpret_cast<const int4*>(nocc + (size_t)batch1 * 128 + l16 * 8);
        int4 v0 = np[0];
        int4 v1 = np[1];
        unsigned nib = 0;
        nib |= (v0.x != 0) ? 1u   : 0u;
        nib |= (v0.y != 0) ? 2u   : 0u;
        nib |= (v0.z != 0) ? 4u   : 0u;
        nib |= (v0.w != 0) ? 8u   : 0u;
        nib |= (v1.x != 0) ? 16u  : 0u;
        nib |= (v1.y != 0) ? 32u  : 0u;
        nib |= (v1.z != 0) ? 64u  : 0u;
        nib |= (v1.w != 0) ? 128u : 0u;
        const int cnt = __popc(nib);
        int incl = cnt;
        const int seg = l16 & 7;
        #pragma unroll
        for (int d = 1; d < 8; d <<= 1) {
            int t = __shfl_up(incl, d, 8);
            if (seg >= d) incl += t;
        }
        int pos = ((l16 >> 3) << 4) + (incl - cnt);
        const int k0 = l16 * 8;
        #pragma unroll
        for (int b = 0; b < 8; b++) {
            if (nib & (1u << b)) lists[bib1][pos++] = k0 + b;
        }
    }
    __syncthreads();

    // ---------------- phase 2: cooperative gather (4 lanes per A-row) ----------------
    {
        const int q = tid & 3;          // quarter within row
        const int G = tid >> 2;         // row index 0..31 (0..15 up, 16..31 dn)
        const int m2 = G >> 4;
        #pragma unroll 1
        for (int p = 0; p < 8; p++) {
            const int* lp = lists[p];
            const int r = lp[G] - (m2 << 6);
            const int off = r * 32 + m2 * 16 + q * 4;   // loop-invariant lane offset (floats)

            float4 acc0 = {0.f, 0.f, 0.f, 0.f};
            float4 acc1 = {0.f, 0.f, 0.f, 0.f};
            float4 acc2 = {0.f, 0.f, 0.f, 0.f};
            float4 acc3 = {0.f, 0.f, 0.f, 0.f};
            #pragma unroll
            for (int t = 0; t < 32; t += 4) {
                const int ka = __builtin_amdgcn_readfirstlane(lp[t + 0]);
                const int kb = __builtin_amdgcn_readfirstlane(lp[t + 1]);
                const int kc = __builtin_amdgcn_readfirstlane(lp[t + 2]);
                const int kd = __builtin_amdgcn_readfirstlane(lp[t + 3]);
                const float4 va = *reinterpret_cast<const float4*>(W + ((size_t)ka << 11) + off);
                const float4 vb = *reinterpret_cast<const float4*>(W + ((size_t)kb << 11) + off);
                const float4 vc = *reinterpret_cast<const float4*>(W + ((size_t)kc << 11) + off);
                const float4 vd = *reinterpret_cast<const float4*>(W + ((size_t)kd << 11) + off);
                acc0.x += va.x; acc0.y += va.y; acc0.z += va.z; acc0.w += va.w;
                acc1.x += vb.x; acc1.y += vb.y; acc1.z += vb.z; acc1.w += vb.w;
                acc2.x += vc.x; acc2.y += vc.y; acc2.z += vc.z; acc2.w += vc.w;
                acc3.x += vd.x; acc3.y += vd.y; acc3.z += vd.z; acc3.w += vd.w;
            }
            float4 acc;
            acc.x = (acc0.x + acc1.x) + (acc2.x + acc3.x);
            acc.y = (acc0.y + acc1.y) + (acc2.y + acc3.y);
            acc.z = (acc0.z + acc1.z) + (acc2.z + acc3.z);
            acc.w = (acc0.w + acc1.w) + (acc2.w + acc3.w);
            *reinterpret_cast<float4*>(&amat[p * MATSTRIDE + G * ROWSTRIDE + q * 4]) = acc;
        }
    }
    __syncthreads();

    // ---------------- phase 3: LU, implicit partial pivoting ----------------
    const int lane = tid & 63;
    const int wave = tid >> 6;          // 0..1
    const int g    = lane >> 3;         // matrix group in wave 0..7
    const int s8   = lane & 7;          // lane in group
    const int bw   = g >> 1;            // batch in wave 0..3
    const int m    = g & 1;             // 0 = up, 1 = dn
    const int bib  = (wave << 2) + bw;  // 0..7
    int batch = blockIdx.x * NB_PER_BLOCK + bib;
    const bool valid = (batch < B);
    if (batch >= B) batch = B - 1;

    float a0[16], a1[16];
    {
        const float* row0 = &amat[bib * MATSTRIDE + (m * 16 + s8) * ROWSTRIDE];
        const float* row1 = row0 + 8 * ROWSTRIDE;
        #pragma unroll
        for (int qq = 0; qq < 4; qq++) {
            float4 v0 = *reinterpret_cast<const float4*>(row0 + qq * 4);
            float4 v1 = *reinterpret_cast<const float4*>(row1 + qq * 4);
            a0[qq*4+0] = v0.x; a0[qq*4+1] = v0.y; a0[qq*4+2] = v0.z; a0[qq*4+3] = v0.w;
            a1[qq*4+0] = v1.x; a1[qq*4+1] = v1.y; a1[qq*4+2] = v1.z; a1[qq*4+3] = v1.w;
        }
    }

    unsigned active = 0xffffu;
    int inv = 0;
    float myd0 = 1.f, myd1 = 1.f;

    #pragma unroll
    for (int k = 0; k < 16; k++) {
        const unsigned act0 = (active >> s8) & 1u;
        const unsigned act1 = (active >> (s8 + 8)) & 1u;
        float av = act0 ? fabsf(a0[k]) : -1.f;
        int idx = s8;
        {
            float av1 = act1 ? fabsf(a1[k]) : -1.f;
            if (av1 > av) { av = av1; idx = s8 + 8; }
        }
        #pragma unroll
        for (int d = 1; d < 8; d <<= 1) {
            float ov = __shfl_xor(av, d, 8);
            int   oi = __shfl_xor(idx, d, 8);
            if (ov > av || (ov == av && oi < idx)) { av = ov; idx = oi; }
        }
        const int p = idx;
        const int plane = p & 7;
        const bool phi = (p & 8) != 0;
        float psel = phi ? a1[k] : a0[k];
        const float pk = __shfl(psel, plane, 8);
        const float rcp = 1.0f / pk;

        if (s8 == p)     myd0 = pk;
        if (s8 + 8 == p) myd1 = pk;
        inv += __popc(active & ((1u << p) - 1u));
        active &= ~(1u << p);

        const float f0 = (act0 && s8 != p)       ? a0[k] * rcp : 0.f;
        const float f1 = (act1 && (s8 + 8) != p) ? a1[k] * rcp : 0.f;

        #pragma unroll
        for (int j = k + 1; j < 16; j++) {
            float sel = phi ? a1[j] : a0[j];
            float pv = __shfl(sel, plane, 8);
            a0[j] = fmaf(-f0, pv, a0[j]);
            a1[j] = fmaf(-f1, pv, a1[j]);
        }
    }

    float ld = logf(fabsf(myd0)) + logf(fabsf(myd1));
    int ng = ((myd0 < 0.f) ? 1 : 0) + ((myd1 < 0.f) ? 1 : 0);
    #pragma unroll
    for (int d = 1; d < 8; d <<= 1) {
        ld += __shfl_xor(ld, d, 8);
        ng += __shfl_xor(ng, d, 8);
    }
    const int neg = (ng + inv) & 1;

    const float ld_o  = __shfl_xor(ld, 8, 16);
    const int   neg_o = __shfl_xor(neg, 8, 16);

    if ((lane & 15) == 0 && valid) {
        out[batch]     = ld + ld_o;                                      // re plane
        out[B + batch] = 3.14159265358979323846f * (float)(neg + neg_o); // im plane
    }
}

extern "C" void kernel_launch(void* const* d_in, const int* in_sizes, int n_in,
                              void* d_out, int out_size, void* d_ws, size_t ws_size,
                              hipStream_t stream) {
    const int* nocc = (const int*)d_in[0];
    const float* W  = (const float*)d_in[1];
    float* out = (float*)d_out;
    const int B = in_sizes[0] / 128;                      // 65536
    const int blocks = (B + NB_PER_BLOCK - 1) / NB_PER_BLOCK;  // 8192
    backflow_kernel<<<blocks, 128, 0, stream>>>(nocc, W, out, B);
}

// Round 3
// 309.865 us; speedup vs baseline: 1.0962x; 1.0962x over previous
//
#include <hip/hip_runtime.h>
#include <math.h>

#define NB 32              // batches per 512-thread block
#define SLAB_F 4096        // slab = 2 W-rows x 2048 floats = 16 KB
#define NSLAB 64           // 128 k-rows / 2 per slab

// R3 structural rewrite: W staged through LDS (L1/MSHR gather path was the
// bottleneck: R1 occupancy +11pts null, R2 MLP x2 null -> per-CU miss-queue
// cap ~0.4 lines/cy). Now:
//  phase 1: 16 lanes/batch -> sorted occupied-k lists (32 entries, ascending;
//           slot 32 = sentinel).
//  main loop (64 slabs, double-buffered): stream W[2k:2k+2, :] into LDS via
//           global_load_lds with PRE-SWIZZLED per-lane global source
//           (col ^= (r&7)<<2, dest linear - m173 pattern), then each lane
//           accumulates its two A-rows (16 cols) from LDS for every occupied
//           k in the slab. Accumulators are already in LU layout -> no amat.
//  LU:      8-lane implicit-partial-pivot LU directly on accumulator regs.
// Swizzle: LDS loc L holds W element col = L ^ ((r&7)<<2), r = (L&2047)>>5
// (involution, 16B-aligned preserving). Read loc = col ^ ((r&7)<<2): breaks
// the 16-rows-same-bank-quad pattern of stride-128B rows.
// Sum order over k is ascending = identical to previous kernel (bitwise).

#define GLD_LDS16(gp, lp) __builtin_amdgcn_global_load_lds( \
    (const __attribute__((address_space(1))) void*)(gp),    \
    (__attribute__((address_space(3))) void*)(lp), 16, 0, 0)

__global__ __launch_bounds__(512, 4) void backflow_kernel(
    const int* __restrict__ nocc,   // (B,128) int32 0/1
    const float* __restrict__ W,    // (128,2048) f32 row-major
    float* __restrict__ out,        // planar: [B re][B im]
    int B)
{
    __shared__ float slab[2 * SLAB_F];   // 32 KB double buffer
    __shared__ int lists[NB][33];        // 4.2 KB; slot 32 = sentinel

    const int tid = threadIdx.x;

    // ---------------- phase 1: occupancy -> k lists ----------------
    {
        const int bib1 = tid >> 4;                 // 0..31
        const int l16  = tid & 15;
        int batch1 = blockIdx.x * NB + bib1;
        if (batch1 >= B) batch1 = B - 1;
        const int4* np = reinterpret_cast<const int4*>(nocc + (size_t)batch1 * 128 + l16 * 8);
        int4 v0 = np[0];
        int4 v1 = np[1];
        unsigned nib = 0;
        nib |= (v0.x != 0) ? 1u   : 0u;
        nib |= (v0.y != 0) ? 2u   : 0u;
        nib |= (v0.z != 0) ? 4u   : 0u;
        nib |= (v0.w != 0) ? 8u   : 0u;
        nib |= (v1.x != 0) ? 16u  : 0u;
        nib |= (v1.y != 0) ? 32u  : 0u;
        nib |= (v1.z != 0) ? 64u  : 0u;
        nib |= (v1.w != 0) ? 128u : 0u;
        const int cnt = __popc(nib);
        int incl = cnt;
        const int seg = l16 & 7;
        #pragma unroll
        for (int d = 1; d < 8; d <<= 1) {
            int t = __shfl_up(incl, d, 8);
            if (seg >= d) incl += t;
        }
        int pos = ((l16 >> 3) << 4) + (incl - cnt);
        const int k0 = l16 * 8;
        #pragma unroll
        for (int b = 0; b < 8; b++) {
            if (nib & (1u << b)) lists[bib1][pos++] = k0 + b;
        }
        if (l16 == 0) lists[bib1][32] = 1 << 30;   // sentinel for k-walk
    }
    __syncthreads();

    // ---------------- thread ids (LU layout from the start) ----------------
    const int lane = tid & 63;
    const int wv   = __builtin_amdgcn_readfirstlane(tid >> 6);  // 0..7, SGPR
    const int g    = lane >> 3;         // 0..7
    const int s8   = lane & 7;
    const int m    = g & 1;             // 0 = up, 1 = dn
    const int bib  = (wv << 2) + (g >> 1);   // 0..31
    int batch = blockIdx.x * NB + bib;
    const bool valid = (batch < B);
    if (!valid) batch = B - 1;

    // ---------------- staging setup (pre-swizzled source) ----------------
    // op o in {0,1}: LDS float idx L = o*2048 + wv*256 + lane*4 (dest linear)
    const int col_l = (wv << 8) + (lane << 2);        // = L & 2047 for both ops
    const int rs    = col_l >> 5;
    const int col_g = col_l ^ ((rs & 7) << 2);        // swizzled source column
    const char* gp0 = (const char*)(W + col_g);           // k row 0 of slab
    const char* gp1 = (const char*)(W + 2048 + col_g);    // k row 1 of slab
    char* const lb_base = (char*)slab + (wv << 10);       // wave-uniform dest

    // prologue: stage slab 0 (k rows 0,1) into buffer 0
    GLD_LDS16(gp0, lb_base);
    GLD_LDS16(gp1, lb_base + 8192);
    gp0 += 16384; gp1 += 16384;

    // my two A-rows: global orbital indices
    const int r0 = lists[bib][(m << 4) + s8] - (m << 6);
    const int r1 = lists[bib][(m << 4) + s8 + 8] - (m << 6);
    // swizzled LDS float-offsets of the four 16B chunks of each row's 16 cols
    int off0[4], off1[4];
    #pragma unroll
    for (int c = 0; c < 4; c++) {
        off0[c] = (r0 << 5) + ((((m << 2) + c) ^ (r0 & 7)) << 2);
        off1[c] = (r1 << 5) + ((((m << 2) + c) ^ (r1 & 7)) << 2);
    }

    float a0[16], a1[16];
    #pragma unroll
    for (int i = 0; i < 16; i++) { a0[i] = 0.f; a1[i] = 0.f; }

    int ptr = 0;
    int nk = lists[bib][0];

    __syncthreads();   // slab 0 resident (compiler drains vmcnt before barrier)

    // ---------------- main loop: stage next, gather current ----------------
    #pragma unroll 1
    for (int s = 0; s < NSLAB; s++) {
        if (s < NSLAB - 1) {
            char* lb = (char*)slab + (((s + 1) & 1) << 14) + (wv << 10);
            GLD_LDS16(gp0, lb);
            GLD_LDS16(gp1, lb + 8192);
            gp0 += 16384; gp1 += 16384;
        }
        const float* cp = slab + ((s & 1) ? SLAB_F : 0);
        const int kend = (s << 1) + 2;
        while (nk < kend) {
            const float* kp = cp + ((nk - (s << 1)) << 11);
            float4 v;
            v = *reinterpret_cast<const float4*>(kp + off0[0]);
            a0[0] += v.x;  a0[1] += v.y;  a0[2] += v.z;  a0[3] += v.w;
            v = *reinterpret_cast<const float4*>(kp + off0[1]);
            a0[4] += v.x;  a0[5] += v.y;  a0[6] += v.z;  a0[7] += v.w;
            v = *reinterpret_cast<const float4*>(kp + off0[2]);
            a0[8] += v.x;  a0[9] += v.y;  a0[10] += v.z; a0[11] += v.w;
            v = *reinterpret_cast<const float4*>(kp + off0[3]);
            a0[12] += v.x; a0[13] += v.y; a0[14] += v.z; a0[15] += v.w;
            v = *reinterpret_cast<const float4*>(kp + off1[0]);
            a1[0] += v.x;  a1[1] += v.y;  a1[2] += v.z;  a1[3] += v.w;
            v = *reinterpret_cast<const float4*>(kp + off1[1]);
            a1[4] += v.x;  a1[5] += v.y;  a1[6] += v.z;  a1[7] += v.w;
            v = *reinterpret_cast<const float4*>(kp + off1[2]);
            a1[8] += v.x;  a1[9] += v.y;  a1[10] += v.z; a1[11] += v.w;
            v = *reinterpret_cast<const float4*>(kp + off1[3]);
            a1[12] += v.x; a1[13] += v.y; a1[14] += v.z; a1[15] += v.w;
            ptr++;
            nk = lists[bib][ptr];   // slot 32 = sentinel
        }
        __syncthreads();
    }

    // ---------------- LU, implicit partial pivoting (on accum regs) ----------------
    unsigned active = 0xffffu;
    int inv = 0;
    float myd0 = 1.f, myd1 = 1.f;

    #pragma unroll
    for (int k = 0; k < 16; k++) {
        const unsigned act0 = (active >> s8) & 1u;
        const unsigned act1 = (active >> (s8 + 8)) & 1u;
        float av = act0 ? fabsf(a0[k]) : -1.f;
        int idx = s8;
        {
            float av1 = act1 ? fabsf(a1[k]) : -1.f;
            if (av1 > av) { av = av1; idx = s8 + 8; }
        }
        #pragma unroll
        for (int d = 1; d < 8; d <<= 1) {
            float ov = __shfl_xor(av, d, 8);
            int   oi = __shfl_xor(idx, d, 8);
            if (ov > av || (ov == av && oi < idx)) { av = ov; idx = oi; }
        }
        const int p = idx;
        const int plane = p & 7;
        const bool phi = (p & 8) != 0;
        float psel = phi ? a1[k] : a0[k];
        const float pk = __shfl(psel, plane, 8);
        const float rcp = 1.0f / pk;

        if (s8 == p)     myd0 = pk;
        if (s8 + 8 == p) myd1 = pk;
        inv += __popc(active & ((1u << p) - 1u));
        active &= ~(1u << p);

        const float f0 = (act0 && s8 != p)       ? a0[k] * rcp : 0.f;
        const float f1 = (act1 && (s8 + 8) != p) ? a1[k] * rcp : 0.f;

        #pragma unroll
        for (int j = k + 1; j < 16; j++) {
            float sel = phi ? a1[j] : a0[j];
            float pv = __shfl(sel, plane, 8);
            a0[j] = fmaf(-f0, pv, a0[j]);
            a1[j] = fmaf(-f1, pv, a1[j]);
        }
    }

    float ld = logf(fabsf(myd0)) + logf(fabsf(myd1));
    int ng = ((myd0 < 0.f) ? 1 : 0) + ((myd1 < 0.f) ? 1 : 0);
    #pragma unroll
    for (int d = 1; d < 8; d <<= 1) {
        ld += __shfl_xor(ld, d, 8);
        ng += __shfl_xor(ng, d, 8);
    }
    const int neg = (ng + inv) & 1;

    const float ld_o  = __shfl_xor(ld, 8, 16);
    const int   neg_o = __shfl_xor(neg, 8, 16);

    if ((lane & 15) == 0 && valid) {
        out[batch]     = ld + ld_o;                                      // re plane
        out[B + batch] = 3.14159265358979323846f * (float)(neg + neg_o); // im plane
    }
}

extern "C" void kernel_launch(void* const* d_in, const int* in_sizes, int n_in,
                              void* d_out, int out_size, void* d_ws, size_t ws_size,
                              hipStream_t stream) {
    const int* nocc = (const int*)d_in[0];
    const float* W  = (const float*)d_in[1];
    float* out = (float*)d_out;
    const int B = in_sizes[0] / 128;                 // 65536
    const int blocks = (B + NB - 1) / NB;            // 2048
    backflow_kernel<<<blocks, 512, 0, stream>>>(nocc, W, out, B);
}

// Round 4
// 271.095 us; speedup vs baseline: 1.2529x; 1.1430x over previous
//
#include <hip/hip_runtime.h>
#include <math.h>

#define NB 32              // batches per 512-thread block
#define SLAB_F 4096        // slab = 2 W-rows x 2048 floats = 16 KB
#define NSLAB 64           // 128 k-rows / 2 per slab

// R4: conflict-free LDS gather by per-lane chunk ROTATION (not swizzle).
//  - LDS slab layout is LINEAR (global_load_lds source linear too).
//  - A lane's read quad = m*4 + chunk (row stride 128B == 0 mod 32 banks,
//    independent of random row r). Reading chunks in order cc=(c+s8)&3 puts
//    the 64 lanes at exactly 8 lanes per bank-quad every instruction slot =
//    the b128 floor (1024B/128B-per-cy = 8 cy), zero conflicts.
//  - Accumulator block c holds physical chunk (c+s8)&3 during the k-loop
//    (all static indices); one-time predicated block-rotation before LU
//    restores physical order. k-sum order unchanged -> bitwise identical.
//  phase 1: 16 lanes/batch -> sorted occupied-k lists (slot 32 = sentinel).
//  main loop (64 slabs, double-buffered): stage W[2s:2s+2,:] via
//    global_load_lds (16B/lane, linear), gather current slab from LDS.
//  LU: 8-lane implicit-partial-pivot LU on accumulator regs (no amat).

#define GLD_LDS16(gp, lp) __builtin_amdgcn_global_load_lds( \
    (const __attribute__((address_space(1))) void*)(gp),    \
    (__attribute__((address_space(3))) void*)(lp), 16, 0, 0)

__global__ __launch_bounds__(512, 4) void backflow_kernel(
    const int* __restrict__ nocc,   // (B,128) int32 0/1
    const float* __restrict__ W,    // (128,2048) f32 row-major
    float* __restrict__ out,        // planar: [B re][B im]
    int B)
{
    __shared__ float slab[2 * SLAB_F];   // 32 KB double buffer
    __shared__ int lists[NB][33];        // 4.2 KB; slot 32 = sentinel

    const int tid = threadIdx.x;

    // ---------------- phase 1: occupancy -> k lists ----------------
    {
        const int bib1 = tid >> 4;                 // 0..31
        const int l16  = tid & 15;
        int batch1 = blockIdx.x * NB + bib1;
        if (batch1 >= B) batch1 = B - 1;
        const int4* np = reinterpret_cast<const int4*>(nocc + (size_t)batch1 * 128 + l16 * 8);
        int4 v0 = np[0];
        int4 v1 = np[1];
        unsigned nib = 0;
        nib |= (v0.x != 0) ? 1u   : 0u;
        nib |= (v0.y != 0) ? 2u   : 0u;
        nib |= (v0.z != 0) ? 4u   : 0u;
        nib |= (v0.w != 0) ? 8u   : 0u;
        nib |= (v1.x != 0) ? 16u  : 0u;
        nib |= (v1.y != 0) ? 32u  : 0u;
        nib |= (v1.z != 0) ? 64u  : 0u;
        nib |= (v1.w != 0) ? 128u : 0u;
        const int cnt = __popc(nib);
        int incl = cnt;
        const int seg = l16 & 7;
        #pragma unroll
        for (int d = 1; d < 8; d <<= 1) {
            int t = __shfl_up(incl, d, 8);
            if (seg >= d) incl += t;
        }
        int pos = ((l16 >> 3) << 4) + (incl - cnt);
        const int k0 = l16 * 8;
        #pragma unroll
        for (int b = 0; b < 8; b++) {
            if (nib & (1u << b)) lists[bib1][pos++] = k0 + b;
        }
        if (l16 == 0) lists[bib1][32] = 1 << 30;   // sentinel for k-walk
    }
    __syncthreads();

    // ---------------- thread ids (LU layout from the start) ----------------
    const int lane = tid & 63;
    const int wv   = __builtin_amdgcn_readfirstlane(tid >> 6);  // 0..7, SGPR
    const int g    = lane >> 3;         // 0..7
    const int s8   = lane & 7;
    const int m    = g & 1;             // 0 = up, 1 = dn
    const int bib  = (wv << 2) + (g >> 1);   // 0..31
    int batch = blockIdx.x * NB + bib;
    const bool valid = (batch < B);
    if (!valid) batch = B - 1;

    // ---------------- staging setup (linear source & dest) ----------------
    const int col_l = (wv << 8) + (lane << 2);            // float idx within k-row
    const char* gp0 = (const char*)(W + col_l);           // k row 0 of slab
    const char* gp1 = (const char*)(W + 2048 + col_l);    // k row 1 of slab
    char* const lb_base = (char*)slab + (wv << 10);       // wave-uniform dest

    // prologue: stage slab 0 (k rows 0,1) into buffer 0
    GLD_LDS16(gp0, lb_base);
    GLD_LDS16(gp1, lb_base + 8192);
    gp0 += 16384; gp1 += 16384;

    // my two A-rows: orbital indices within spin block
    const int* lp = lists[bib];
    const int r0 = lp[(m << 4) + s8] - (m << 6);
    const int r1 = lp[(m << 4) + s8 + 8] - (m << 6);
    // rotated chunk offsets: step c reads physical chunk (c+s8)&3
    int off0[4], off1[4];
    #pragma unroll
    for (int c = 0; c < 4; c++) {
        const int cc = (c + s8) & 3;
        off0[c] = (r0 << 5) + (m << 4) + (cc << 2);
        off1[c] = (r1 << 5) + (m << 4) + (cc << 2);
    }

    float a0[16], a1[16];
    #pragma unroll
    for (int i = 0; i < 16; i++) { a0[i] = 0.f; a1[i] = 0.f; }

    int ptr = 0;
    int nk = lp[0];

    __syncthreads();   // slab 0 resident (compiler drains vmcnt before barrier)

    // ---------------- main loop: stage next, gather current ----------------
    #pragma unroll 1
    for (int s = 0; s < NSLAB; s++) {
        if (s < NSLAB - 1) {
            char* lb = (char*)slab + (((s + 1) & 1) << 14) + (wv << 10);
            GLD_LDS16(gp0, lb);
            GLD_LDS16(gp1, lb + 8192);
            gp0 += 16384; gp1 += 16384;
        }
        const float* cp = slab + ((s & 1) ? SLAB_F : 0);
        const int kend = (s << 1) + 2;
        while (nk < kend) {
            const float* kp = cp + ((nk & 1) << 11);   // k-local row in slab
            float4 v;
            v = *reinterpret_cast<const float4*>(kp + off0[0]);
            a0[0] += v.x;  a0[1] += v.y;  a0[2] += v.z;  a0[3] += v.w;
            v = *reinterpret_cast<const float4*>(kp + off0[1]);
            a0[4] += v.x;  a0[5] += v.y;  a0[6] += v.z;  a0[7] += v.w;
            v = *reinterpret_cast<const float4*>(kp + off0[2]);
            a0[8] += v.x;  a0[9] += v.y;  a0[10] += v.z; a0[11] += v.w;
            v = *reinterpret_cast<const float4*>(kp + off0[3]);
            a0[12] += v.x; a0[13] += v.y; a0[14] += v.z; a0[15] += v.w;
            v = *reinterpret_cast<const float4*>(kp + off1[0]);
            a1[0] += v.x;  a1[1] += v.y;  a1[2] += v.z;  a1[3] += v.w;
            v = *reinterpret_cast<const float4*>(kp + off1[1]);
            a1[4] += v.x;  a1[5] += v.y;  a1[6] += v.z;  a1[7] += v.w;
            v = *reinterpret_cast<const float4*>(kp + off1[2]);
            a1[8] += v.x;  a1[9] += v.y;  a1[10] += v.z; a1[11] += v.w;
            v = *reinterpret_cast<const float4*>(kp + off1[3]);
            a1[12] += v.x; a1[13] += v.y; a1[14] += v.z; a1[15] += v.w;
            ptr++;
            nk = lp[ptr];   // slot 32 = sentinel
        }
        __syncthreads();
    }

    // ---------------- un-rotate accumulator blocks (one-time) ----------------
    // block c holds physical chunk (c+s8)&3; want phys[p] = block[(p-s8)&3]
    // = right-rotate blocks by r=s8&3 (two predicated stages, static indices).
    {
        const bool rb1 = (s8 & 1) != 0;
        const bool rb2 = (s8 & 2) != 0;
        float t[16];
        #pragma unroll
        for (int j = 0; j < 4; j++) {
            t[0  + j] = rb1 ? a0[12 + j] : a0[0  + j];
            t[4  + j] = rb1 ? a0[0  + j] : a0[4  + j];
            t[8  + j] = rb1 ? a0[4  + j] : a0[8  + j];
            t[12 + j] = rb1 ? a0[8  + j] : a0[12 + j];
        }
        #pragma unroll
        for (int j = 0; j < 4; j++) {
            a0[0  + j] = rb2 ? t[8  + j] : t[0  + j];
            a0[4  + j] = rb2 ? t[12 + j] : t[4  + j];
            a0[8  + j] = rb2 ? t[0  + j] : t[8  + j];
            a0[12 + j] = rb2 ? t[4  + j] : t[12 + j];
        }
        #pragma unroll
        for (int j = 0; j < 4; j++) {
            t[0  + j] = rb1 ? a1[12 + j] : a1[0  + j];
            t[4  + j] = rb1 ? a1[0  + j] : a1[4  + j];
            t[8  + j] = rb1 ? a1[4  + j] : a1[8  + j];
            t[12 + j] = rb1 ? a1[8  + j] : a1[12 + j];
        }
        #pragma unroll
        for (int j = 0; j < 4; j++) {
            a1[0  + j] = rb2 ? t[8  + j] : t[0  + j];
            a1[4  + j] = rb2 ? t[12 + j] : t[4  + j];
            a1[8  + j] = rb2 ? t[0  + j] : t[8  + j];
            a1[12 + j] = rb2 ? t[4  + j] : t[12 + j];
        }
    }

    // ---------------- LU, implicit partial pivoting (on accum regs) ----------------
    unsigned active = 0xffffu;
    int inv = 0;
    float myd0 = 1.f, myd1 = 1.f;

    #pragma unroll
    for (int k = 0; k < 16; k++) {
        const unsigned act0 = (active >> s8) & 1u;
        const unsigned act1 = (active >> (s8 + 8)) & 1u;
        float av = act0 ? fabsf(a0[k]) : -1.f;
        int idx = s8;
        {
            float av1 = act1 ? fabsf(a1[k]) : -1.f;
            if (av1 > av) { av = av1; idx = s8 + 8; }
        }
        #pragma unroll
        for (int d = 1; d < 8; d <<= 1) {
            float ov = __shfl_xor(av, d, 8);
            int   oi = __shfl_xor(idx, d, 8);
            if (ov > av || (ov == av && oi < idx)) { av = ov; idx = oi; }
        }
        const int p = idx;
        const int plane = p & 7;
        const bool phi = (p & 8) != 0;
        float psel = phi ? a1[k] : a0[k];
        const float pk = __shfl(psel, plane, 8);
        const float rcp = 1.0f / pk;

        if (s8 == p)     myd0 = pk;
        if (s8 + 8 == p) myd1 = pk;
        inv += __popc(active & ((1u << p) - 1u));
        active &= ~(1u << p);

        const float f0 = (act0 && s8 != p)       ? a0[k] * rcp : 0.f;
        const float f1 = (act1 && (s8 + 8) != p) ? a1[k] * rcp : 0.f;

        #pragma unroll
        for (int j = k + 1; j < 16; j++) {
            float sel = phi ? a1[j] : a0[j];
            float pv = __shfl(sel, plane, 8);
            a0[j] = fmaf(-f0, pv, a0[j]);
            a1[j] = fmaf(-f1, pv, a1[j]);
        }
    }

    float ld = logf(fabsf(myd0)) + logf(fabsf(myd1));
    int ng = ((myd0 < 0.f) ? 1 : 0) + ((myd1 < 0.f) ? 1 : 0);
    #pragma unroll
    for (int d = 1; d < 8; d <<= 1) {
        ld += __shfl_xor(ld, d, 8);
        ng += __shfl_xor(ng, d, 8);
    }
    const int neg = (ng + inv) & 1;

    const float ld_o  = __shfl_xor(ld, 8, 16);
    const int   neg_o = __shfl_xor(neg, 8, 16);

    if ((lane & 15) == 0 && valid) {
        out[batch]     = ld + ld_o;                                      // re plane
        out[B + batch] = 3.14159265358979323846f * (float)(neg + neg_o); // im plane
    }
}

extern "C" void kernel_launch(void* const* d_in, const int* in_sizes, int n_in,
                              void* d_out, int out_size, void* d_ws, size_t ws_size,
                              hipStream_t stream) {
    const int* nocc = (const int*)d_in[0];
    const float* W  = (const float*)d_in[1];
    float* out = (float*)d_out;
    const int B = in_sizes[0] / 128;                 // 65536
    const int blocks = (B + NB - 1) / NB;            // 2048
    backflow_kernel<<<blocks, 512, 0, stream>>>(nocc, W, out, B);
}